// Round 1
// baseline (653.761 us; speedup 1.0000x reference)
//
#include <hip/hip_runtime.h>

typedef unsigned short u16;
typedef unsigned int   u32;
typedef __attribute__((ext_vector_type(8))) short s16x8;   // 8 x bf16 MFMA frag
typedef __attribute__((ext_vector_type(4))) float f32x4;

__device__ __forceinline__ u16 f2bf(float f) {
  u32 u = __builtin_bit_cast(u32, f);
  return (u16)((u + 0x7FFFu + ((u >> 16) & 1u)) >> 16);   // RNE
}
__device__ __forceinline__ float bf2f(u16 h) {
  return __builtin_bit_cast(float, (u32)h << 16);
}

// ---------------- K0: weight f32 -> bf16 ----------------
__global__ __launch_bounds__(256) void k_wcvt(const float* __restrict__ wq,
                                              const float* __restrict__ wp,
                                              u16* __restrict__ wq_bf,
                                              u16* __restrict__ wp_bf) {
  int i = blockIdx.x * 256 + threadIdx.x;
  if (i < 576 * 192) wq_bf[i] = f2bf(wq[i]);
  if (i < 192 * 192) wp_bf[i] = f2bf(wp[i]);
}

// ---------------- K1: qkv 1x1 conv (GEMM M=576,K=192) on shuffled frame ----
// Block: one shuffled row h1 (256 pixels). Gathers x via sigma^-1, writes
// qkv1 in NCHW bf16 (contiguous per channel plane).
__global__ __launch_bounds__(256) void k_qkv(const float* __restrict__ x,
                                             const u16* __restrict__ wq,
                                             u16* __restrict__ qkv1) {
  __shared__ __align__(16) u16 Xs[256 * 200];        // [n=256][k=192 pad 200]
  __shared__ __align__(16) u16 WOut[64 * 264];       // W view [64][200] / OutT [64][264]
  const int t  = threadIdx.x;
  const int b  = blockIdx.y;
  const int h1 = blockIdx.x;                          // shuffled row h'
  // sigma^-1(h1, n=t): original pixel
  const int ho = ((t >> 2) & 3) * 64 + (h1 >> 2);
  const int wo = (t & 3) * 64 + ((h1 & 3) << 4) + (t >> 4);
  const float* src = x + (size_t)b * 12582912 + (size_t)ho * 256 + wo;
#pragma unroll 8
  for (int c = 0; c < 192; c += 2) {
    float v0 = src[(size_t)c * 65536];
    float v1 = src[(size_t)(c + 1) * 65536];
    *(u32*)&Xs[t * 200 + c] = (u32)f2bf(v0) | ((u32)f2bf(v1) << 16);
  }
  const int lane = t & 63, wid = t >> 6;
  const int lm = lane & 15, lk = lane >> 4;
  u16* const outb = qkv1 + (size_t)b * 37748736 + (size_t)h1 * 256;

  for (int mt = 0; mt < 9; ++mt) {
    __syncthreads();
    { // stage W tile [64][192]
      const int row = t >> 2, col = (t & 3) * 48;
      const u16* wsrc = wq + (size_t)(mt * 64 + row) * 192 + col;
      u16* wdst = &WOut[row * 200 + col];
#pragma unroll
      for (int j = 0; j < 48; j += 8)
        *(uint4*)(wdst + j) = *(const uint4*)(wsrc + j);
    }
    __syncthreads();
    f32x4 acc[4][4];
#pragma unroll
    for (int i = 0; i < 4; ++i) {
#pragma unroll
      for (int j = 0; j < 4; ++j) acc[i][j] = f32x4{0.f, 0.f, 0.f, 0.f};
    }
#pragma unroll
    for (int k0 = 0; k0 < 192; k0 += 32) {
      s16x8 af[4], bv[4];
#pragma unroll
      for (int mf = 0; mf < 4; ++mf)
        af[mf] = *(const s16x8*)&WOut[(mf * 16 + lm) * 200 + k0 + lk * 8];
#pragma unroll
      for (int nf = 0; nf < 4; ++nf)
        bv[nf] = *(const s16x8*)&Xs[(wid * 64 + nf * 16 + lm) * 200 + k0 + lk * 8];
#pragma unroll
      for (int mf = 0; mf < 4; ++mf) {
#pragma unroll
        for (int nf = 0; nf < 4; ++nf)
          acc[mf][nf] = __builtin_amdgcn_mfma_f32_16x16x32_bf16(af[mf], bv[nf], acc[mf][nf], 0, 0, 0);
      }
    }
    __syncthreads();                 // W reads done; reuse region as OutT [m][n]
#pragma unroll
    for (int mf = 0; mf < 4; ++mf) {
#pragma unroll
      for (int nf = 0; nf < 4; ++nf) {
        const int n = wid * 64 + nf * 16 + lm;
        const int m = mf * 16 + lk * 4;
#pragma unroll
        for (int r = 0; r < 4; ++r)
          WOut[(m + r) * 264 + n] = f2bf(acc[mf][nf][r]);
      }
    }
    __syncthreads();
    { // coalesced NCHW store: thread t -> (m = t/4, quarter c4 = t%3)
      const int m = t >> 2, c4 = t & 3;
      u16* dst = outb + (size_t)(mt * 64 + m) * 65536 + c4 * 64;
#pragma unroll
      for (int j = 0; j < 64; j += 8)
        *(uint4*)(dst + j) = *(const uint4*)&WOut[m * 264 + c4 * 64 + j];
    }
  }
}

// ---------------- K2: depthwise 3x3, pad 1, NCHW bf16 -> NCHW bf16 --------
__global__ __launch_bounds__(256) void k_dw(const u16* __restrict__ qkv1,
                                            const float* __restrict__ wdw,
                                            u16* __restrict__ qkvb) {
  const int t = threadIdx.x;
  const int c = blockIdx.y;
  const int b = blockIdx.z;
  const int s0 = (blockIdx.x * 256 + t) * 8;
  const int h0 = s0 >> 8, w0 = s0 & 255;
  const size_t cb = ((size_t)b * 576 + c) * 65536;
  const u16* in = qkv1 + cb;
  float w9[9];
#pragma unroll
  for (int i = 0; i < 9; ++i) w9[i] = wdw[c * 9 + i];
  float acc[8] = {0.f,0.f,0.f,0.f,0.f,0.f,0.f,0.f};
#pragma unroll
  for (int ky = 0; ky < 3; ++ky) {
    const int nh = h0 + ky - 1;
    if (nh < 0 || nh > 255) continue;
    const u16* row = in + (size_t)nh * 256 + w0;
    uint4 mid = *(const uint4*)row;
    float e[10];
    e[0] = (w0 > 0) ? bf2f(row[-1]) : 0.f;
    u32 uu[4] = {mid.x, mid.y, mid.z, mid.w};
#pragma unroll
    for (int q = 0; q < 4; ++q) {
      e[1 + 2 * q] = bf2f((u16)(uu[q] & 0xffffu));
      e[2 + 2 * q] = bf2f((u16)(uu[q] >> 16));
    }
    e[9] = (w0 < 248) ? bf2f(row[8]) : 0.f;
#pragma unroll
    for (int kx = 0; kx < 3; ++kx) {
      const float wk = w9[ky * 3 + kx];
#pragma unroll
      for (int j = 0; j < 8; ++j) acc[j] += wk * e[j + kx];
    }
  }
  u32 o[4];
#pragma unroll
  for (int q = 0; q < 4; ++q)
    o[q] = (u32)f2bf(acc[2 * q]) | ((u32)f2bf(acc[2 * q + 1]) << 16);
  *(uint4*)(qkvb + cb + s0) = make_uint4(o[0], o[1], o[2], o[3]);
}

// ---------------- K3: raw-reshape windowed MSA ----------------------------
// Flat-index replication: reads qkvb flat at p'*576 + j*192 + head*24 + d,
// writes attnb flat at p'*192 + head*24 + d. One thread = (window, head).
__global__ __launch_bounds__(256) void k_msa(const u16* __restrict__ qkvb,
                                             u16* __restrict__ attnb) {
  const int t = threadIdx.x;
  const int b = blockIdx.y;
  const int g = blockIdx.x * 32 + (t >> 3);
  const int head = t & 7;
  const int gh = g >> 7, gw = g & 127;
  const u16* qb = qkvb + (size_t)b * 37748736;
  u16* ab = attnb + (size_t)b * 12582912;
  int poff[4];
#pragma unroll
  for (int tt = 0; tt < 4; ++tt)
    poff[tt] = (2 * gh + (tt >> 1)) * 256 + 2 * gw + (tt & 1);
  uint4 kreg[4][3], vreg[4][3];
#pragma unroll
  for (int tt = 0; tt < 4; ++tt) {
    const u16* sp = qb + (size_t)poff[tt] * 576 + head * 24;
#pragma unroll
    for (int cc = 0; cc < 3; ++cc) {
      kreg[tt][cc] = *(const uint4*)(sp + 192 + cc * 8);
      vreg[tt][cc] = *(const uint4*)(sp + 384 + cc * 8);
    }
  }
#pragma unroll
  for (int tq = 0; tq < 4; ++tq) {
    const u16* sp = qb + (size_t)poff[tq] * 576 + head * 24;
    float qf[24];
#pragma unroll
    for (int cc = 0; cc < 3; ++cc) {
      uint4 v = *(const uint4*)(sp + cc * 8);
      u32 uu[4] = {v.x, v.y, v.z, v.w};
#pragma unroll
      for (int q = 0; q < 4; ++q) {
        qf[cc * 8 + 2 * q]     = bf2f((u16)(uu[q] & 0xffffu));
        qf[cc * 8 + 2 * q + 1] = bf2f((u16)(uu[q] >> 16));
      }
    }
    float s[4];
#pragma unroll
    for (int tk = 0; tk < 4; ++tk) {
      float d = 0.f;
#pragma unroll
      for (int cc = 0; cc < 3; ++cc) {
        uint4 v = kreg[tk][cc];
        u32 uu[4] = {v.x, v.y, v.z, v.w};
#pragma unroll
        for (int q = 0; q < 4; ++q) {
          d += qf[cc * 8 + 2 * q]     * bf2f((u16)(uu[q] & 0xffffu));
          d += qf[cc * 8 + 2 * q + 1] * bf2f((u16)(uu[q] >> 16));
        }
      }
      s[tk] = d * 0.35355339059327373f;   // SCALE = HEADS^-0.5
    }
    float mx = fmaxf(fmaxf(s[0], s[1]), fmaxf(s[2], s[3]));
    float e0 = __expf(s[0] - mx), e1 = __expf(s[1] - mx);
    float e2 = __expf(s[2] - mx), e3 = __expf(s[3] - mx);
    float inv = 1.f / (e0 + e1 + e2 + e3);
    float aw[4] = {e0 * inv, e1 * inv, e2 * inv, e3 * inv};
    float of[24];
#pragma unroll
    for (int dd = 0; dd < 24; ++dd) of[dd] = 0.f;
#pragma unroll
    for (int tk = 0; tk < 4; ++tk) {
#pragma unroll
      for (int cc = 0; cc < 3; ++cc) {
        uint4 v = vreg[tk][cc];
        u32 uu[4] = {v.x, v.y, v.z, v.w};
#pragma unroll
        for (int q = 0; q < 4; ++q) {
          of[cc * 8 + 2 * q]     += aw[tk] * bf2f((u16)(uu[q] & 0xffffu));
          of[cc * 8 + 2 * q + 1] += aw[tk] * bf2f((u16)(uu[q] >> 16));
        }
      }
    }
    u16* dst = ab + (size_t)poff[tq] * 192 + head * 24;
#pragma unroll
    for (int cc = 0; cc < 3; ++cc) {
      u32 o0 = (u32)f2bf(of[cc * 8 + 0]) | ((u32)f2bf(of[cc * 8 + 1]) << 16);
      u32 o1 = (u32)f2bf(of[cc * 8 + 2]) | ((u32)f2bf(of[cc * 8 + 3]) << 16);
      u32 o2 = (u32)f2bf(of[cc * 8 + 4]) | ((u32)f2bf(of[cc * 8 + 5]) << 16);
      u32 o3 = (u32)f2bf(of[cc * 8 + 6]) | ((u32)f2bf(of[cc * 8 + 7]) << 16);
      *(uint4*)(dst + cc * 8) = make_uint4(o0, o1, o2, o3);
    }
  }
}

// ---------------- K4: proj 1x1 (GEMM M=192,K=192) + shuffle_back ----------
__global__ __launch_bounds__(256) void k_proj(const u16* __restrict__ attnb,
                                              const u16* __restrict__ wp,
                                              float* __restrict__ out) {
  __shared__ __align__(16) u16 Xs[256 * 200];
  __shared__ __align__(16) unsigned char WOutRaw[34816]; // Wt [64][200] u16 / OutF [256][34] f32
  u16* Wt = (u16*)WOutRaw;
  float* OutF = (float*)WOutRaw;
  const int t  = threadIdx.x;
  const int b  = blockIdx.y;
  const int hs = blockIdx.x;                 // shuffled-frame row of proj input
  const u16* ab = attnb + (size_t)b * 12582912 + (size_t)hs * 256 + t;
#pragma unroll 8
  for (int c = 0; c < 192; c += 2) {
    u16 v0 = ab[(size_t)c * 65536];
    u16 v1 = ab[(size_t)(c + 1) * 65536];
    *(u32*)&Xs[t * 200 + c] = (u32)v0 | ((u32)v1 << 16);
  }
  const int lane = t & 63, wid = t >> 6;
  const int lm = lane & 15, lk = lane >> 4;
  float* const ob = out + (size_t)b * 12582912;
  const int hq_base = hs >> 2;
  const int wq_base = (hs & 3) << 4;

  for (int mt = 0; mt < 3; ++mt) {
    __syncthreads();
    {
      const int row = t >> 2, col = (t & 3) * 48;
      const u16* wsrc = wp + (size_t)(mt * 64 + row) * 192 + col;
      u16* wdst = &Wt[row * 200 + col];
#pragma unroll
      for (int j = 0; j < 48; j += 8)
        *(uint4*)(wdst + j) = *(const uint4*)(wsrc + j);
    }
    __syncthreads();
    f32x4 acc[4][4];
#pragma unroll
    for (int i = 0; i < 4; ++i) {
#pragma unroll
      for (int j = 0; j < 4; ++j) acc[i][j] = f32x4{0.f, 0.f, 0.f, 0.f};
    }
#pragma unroll
    for (int k0 = 0; k0 < 192; k0 += 32) {
      s16x8 af[4], bv[4];
#pragma unroll
      for (int mf = 0; mf < 4; ++mf)
        af[mf] = *(const s16x8*)&Wt[(mf * 16 + lm) * 200 + k0 + lk * 8];
#pragma unroll
      for (int nf = 0; nf < 4; ++nf)
        bv[nf] = *(const s16x8*)&Xs[(wid * 64 + nf * 16 + lm) * 200 + k0 + lk * 8];
#pragma unroll
      for (int mf = 0; mf < 4; ++mf) {
#pragma unroll
        for (int nf = 0; nf < 4; ++nf)
          acc[mf][nf] = __builtin_amdgcn_mfma_f32_16x16x32_bf16(af[mf], bv[nf], acc[mf][nf], 0, 0, 0);
      }
    }
    // epilogue in two m-halves (LDS reuse of Wt region)
#pragma unroll
    for (int half = 0; half < 2; ++half) {
      __syncthreads();
#pragma unroll
      for (int mh = 0; mh < 2; ++mh) {
        const int mf = half * 2 + mh;
#pragma unroll
        for (int nf = 0; nf < 4; ++nf) {
          const int n = wid * 64 + nf * 16 + lm;
          const int ml = mh * 16 + lk * 4;
          float2* o = (float2*)&OutF[n * 34 + ml];
          o[0] = make_float2(acc[mf][nf][0], acc[mf][nf][1]);
          o[1] = make_float2(acc[mf][nf][2], acc[mf][nf][3]);
        }
      }
      __syncthreads();
      {
        const int col = t & 31;     // co within half
        const int r0 = t >> 5;      // 0..7
#pragma unroll
        for (int ri = 0; ri < 2; ++ri) {
          const int r = r0 + ri * 8;
          const int co = mt * 64 + half * 32 + col;
          const int hq = ((r >> 2) & 3) * 64 + hq_base;   // tau(hs, ws=16j+r)
          const int wq0 = (r & 3) * 64 + wq_base;
          float* dst = ob + (size_t)co * 65536 + (size_t)hq * 256 + wq0;
#pragma unroll
          for (int jj = 0; jj < 16; jj += 4) {
            float4 vv = make_float4(OutF[((jj + 0) * 16 + r) * 34 + col],
                                    OutF[((jj + 1) * 16 + r) * 34 + col],
                                    OutF[((jj + 2) * 16 + r) * 34 + col],
                                    OutF[((jj + 3) * 16 + r) * 34 + col]);
            *(float4*)(dst + jj) = vv;
          }
        }
      }
    }
  }
}

extern "C" void kernel_launch(void* const* d_in, const int* in_sizes, int n_in,
                              void* d_out, int out_size, void* d_ws, size_t ws_size,
                              hipStream_t stream) {
  const float* x   = (const float*)d_in[0];
  const float* wq  = (const float*)d_in[1];
  const float* wdw = (const float*)d_in[2];
  const float* wpr = (const float*)d_in[3];
  float* out = (float*)d_out;
  u16* ws = (u16*)d_ws;
  // workspace layout (u16 units): wq_bf | wp_bf | qkv1 (reused as attn) | qkvb
  u16* wq_bf = ws;
  u16* wp_bf = ws + 110592;
  u16* qkv1  = ws + 147456;                       // 4*576*65536 bf16 (NCHW)
  u16* qkvb  = qkv1 + (size_t)150994944;          // 4*576*65536 bf16 (NCHW)
  u16* attnb = qkv1;                              // reuse: qkv1 dead after k_dw

  hipLaunchKernelGGL(k_wcvt, dim3(432), dim3(256), 0, stream, wq, wpr, wq_bf, wp_bf);
  hipLaunchKernelGGL(k_qkv,  dim3(256, 4), dim3(256), 0, stream, x, wq_bf, qkv1);
  hipLaunchKernelGGL(k_dw,   dim3(32, 576, 4), dim3(256), 0, stream, qkv1, wdw, qkvb);
  hipLaunchKernelGGL(k_msa,  dim3(512, 4), dim3(256), 0, stream, qkvb, attnb);
  hipLaunchKernelGGL(k_proj, dim3(256, 4), dim3(256), 0, stream, attnb, wp_bf, out);
}